// Round 3
// baseline (1102.900 us; speedup 1.0000x reference)
//
#include <hip/hip_runtime.h>

#define NFEAT 128
#define HID 16
#define NOUT 2
#define NGRAPH 64

#define NBUCK 128          // node buckets of 1024 (covers 131072 >= N)
#define NCB 256            // count/scatter blocks (contiguous edge chunks)
#define SPLITS_D 4
#define SPLITS_A 4
#define SPLITS_E 8
#define NPART (NBUCK * SPLITS_E)   // e2pool partial rows
#define PSTRIDE 192                // 128 sums + 64 counts

// ---------------- init: zero agg1, deg=1 (self loop) -----------------------
__global__ __launch_bounds__(256) void k_init(float* agg1, float* deg, int N) {
    int i = blockIdx.x * 256 + threadIdx.x;
    if (i < N * HID) agg1[i] = 0.0f;
    if (i < N) deg[i] = 1.0f;
}

// ---------------- count: per-(chunk, bucket) histogram ---------------------
__global__ __launch_bounds__(256) void k_count(const int* __restrict__ dst, int* __restrict__ gcnt, int E) {
    __shared__ int c[NBUCK];
    int t = threadIdx.x;
    if (t < NBUCK) c[t] = 0;
    __syncthreads();
    int chunk = (E + NCB - 1) / NCB;
    int start = blockIdx.x * chunk;
    int end = min(E, start + chunk);
    for (int e = start + t; e < end; e += 256)
        atomicAdd(&c[dst[e] >> 10], 1);
    __syncthreads();
    if (t < NBUCK) gcnt[t * NCB + blockIdx.x] = c[t];
}

// ---------------- scan: exclusive prefix over 32768 counts -----------------
__global__ __launch_bounds__(1024) void k_scan(int* gcnt) {
    __shared__ int part[1024];
    int t = threadIdx.x;
    int base = t * 32;
    int v[32];
    int s = 0;
    #pragma unroll
    for (int i = 0; i < 32; i++) { v[i] = gcnt[base + i]; s += v[i]; }
    part[t] = s;
    __syncthreads();
    for (int off = 1; off < 1024; off <<= 1) {
        int a = part[t];
        int b = (t >= off) ? part[t - off] : 0;
        __syncthreads();
        part[t] = a + b;
        __syncthreads();
    }
    int ex = (t == 0) ? 0 : part[t - 1];
    #pragma unroll
    for (int i = 0; i < 32; i++) { int tmp = gcnt[base + i]; gcnt[base + i] = ex; ex += tmp; }
}

// ---------------- scatter: bucket edges, packed (dloc<<17)|src -------------
__global__ __launch_bounds__(256) void k_scatter(const int* __restrict__ src, const int* __restrict__ dst,
                                                 const int* __restrict__ gcnt,
                                                 unsigned int* __restrict__ bpk, int E) {
    __shared__ int off[NBUCK];
    int t = threadIdx.x;
    if (t < NBUCK) off[t] = gcnt[t * NCB + blockIdx.x];
    __syncthreads();
    int chunk = (E + NCB - 1) / NCB;
    int start = blockIdx.x * chunk;
    int end = min(E, start + chunk);
    for (int e = start + t; e < end; e += 256) {
        int s = src[e];
        int d = dst[e];
        int k = d >> 10;
        int pos = atomicAdd(&off[k], 1);
        bpk[pos] = ((unsigned)(d & 1023) << 17) | (unsigned)s;
    }
}

// ---------------- deg via per-bucket LDS histogram -------------------------
__global__ __launch_bounds__(256) void k_bdeg(const unsigned int* __restrict__ bpk, const int* __restrict__ gcnt,
                                              float* __restrict__ deg, int E, int N) {
    __shared__ int hist[1024];
    int t = threadIdx.x;
    int k = blockIdx.x >> 2, sp = blockIdx.x & (SPLITS_D - 1);
    for (int i = t; i < 1024; i += 256) hist[i] = 0;
    __syncthreads();
    int bstart = gcnt[k * NCB];
    int bend = (k < NBUCK - 1) ? gcnt[(k + 1) * NCB] : E;
    int len = bend - bstart;
    int es = bstart + (int)((long long)len * sp / SPLITS_D);
    int ee = bstart + (int)((long long)len * (sp + 1) / SPLITS_D);
    for (int e = es + t; e < ee; e += 256)
        atomicAdd(&hist[bpk[e] >> 17], 1);
    __syncthreads();
    int nbase = k << 10;
    for (int i = t; i < 1024; i += 256) {
        int h = hist[i];
        int node = nbase + i;
        if (h && node < N) atomicAdd(&deg[node], (float)h);
    }
}

// ---------------- dinv = 1/sqrt(deg) (in place) ----------------------------
__global__ __launch_bounds__(256) void k_dinv(float* deg, int N) {
    int i = blockIdx.x * 256 + threadIdx.x;
    if (i < N) deg[i] = 1.0f / sqrtf(deg[i]);
}

// ---------------- h1s = dinv * (x @ W1) ------------------------------------
__global__ __launch_bounds__(256) void k_xw1(const float* __restrict__ x, const float* __restrict__ W1,
                                             const float* __restrict__ dinv,
                                             float* __restrict__ h1s, int N) {
    __shared__ float sW[NFEAT * HID];
    __shared__ float sx[16 * 132];
    int t = threadIdx.x;
    #pragma unroll
    for (int i = 0; i < NFEAT * HID; i += 256) sW[i + t] = W1[i + t];

    int local = t >> 4;
    int h     = t & 15;
    int n = blockIdx.x * 16 + local;

    if (n < N) {
        const float4* xr = (const float4*)(x + (size_t)n * NFEAT);
        float4 a = xr[h * 2];
        float4 b = xr[h * 2 + 1];
        float* sp = sx + local * 132 + h * 8;
        ((float4*)sp)[0] = a;
        ((float4*)sp)[1] = b;
    }
    __syncthreads();
    if (n >= N) return;

    const float* row = sx + local * 132;
    float acc = 0.0f;
    #pragma unroll
    for (int kk = 0; kk < NFEAT; kk++) acc += row[kk] * sW[kk * HID + h];

    h1s[(size_t)n * HID + h] = acc * dinv[n];
}

// ---------------- agg1: bucketed LDS accumulation of h1s[src] --------------
// split 0 seeds the self-loop term h1s[d]; flush = contiguous coalesced atomics
__global__ __launch_bounds__(256) void k_agg(const unsigned int* __restrict__ bpk, const int* __restrict__ gcnt,
                                             const float* __restrict__ h1s,
                                             float* __restrict__ agg1, int E, int N) {
    __shared__ float acc[1024 * HID];       // 64 KB
    int t = threadIdx.x;
    int k = blockIdx.x >> 2, sp = blockIdx.x & (SPLITS_A - 1);
    int nbase = k << 10;
    for (int i = t; i < 1024 * HID; i += 256) {
        float v = 0.0f;
        if (sp == 0) {
            int node = nbase + (i >> 4);
            if (node < N) v = h1s[(size_t)node * HID + (i & 15)];
        }
        acc[i] = v;
    }
    __syncthreads();
    int bstart = gcnt[k * NCB];
    int bend = (k < NBUCK - 1) ? gcnt[(k + 1) * NCB] : E;
    int len = bend - bstart;
    int es = bstart + (int)((long long)len * sp / SPLITS_A);
    int ee = bstart + (int)((long long)len * (sp + 1) / SPLITS_A);
    int f = t & 15;
    for (int e = es + (t >> 4); e < ee; e += 16) {
        unsigned v = bpk[e];
        int s = v & 0x1FFFF;
        int dloc = v >> 17;
        atomicAdd(&acc[(dloc << 4) | f], h1s[(size_t)s * HID + f]);
    }
    __syncthreads();
    for (int i = t; i < 1024 * HID; i += 256) {
        float v = acc[i];
        int node = nbase + (i >> 4);
        if (v != 0.0f && node < N)
            atomicAdd(&agg1[(size_t)node * HID + (i & 15)], v);
    }
}

// ---------------- PReLU(dinv*agg1 + b1) @ W2 ; t2s = dinv*t2 ---------------
__global__ __launch_bounds__(256) void k_mid(const float* __restrict__ agg1, const float* __restrict__ b1,
                                             const float* __restrict__ prelu_a, const float* __restrict__ W2,
                                             const float* __restrict__ dinv,
                                             float* __restrict__ t2s, int N) {
    int n = blockIdx.x * 256 + threadIdx.x;
    if (n >= N) return;
    float a = prelu_a[0];
    float di = dinv[n];
    float v[HID];
    const float4* p = (const float4*)(agg1 + (size_t)n * HID);
    #pragma unroll
    for (int i = 0; i < 4; i++) {
        float4 q = p[i];
        v[4 * i + 0] = q.x; v[4 * i + 1] = q.y; v[4 * i + 2] = q.z; v[4 * i + 3] = q.w;
    }
    float o0 = 0.0f, o1 = 0.0f;
    #pragma unroll
    for (int i = 0; i < HID; i++) {
        float tv = di * v[i] + b1[i];
        tv = (tv >= 0.0f) ? tv : a * tv;
        o0 += tv * W2[i * 2 + 0];
        o1 += tv * W2[i * 2 + 1];
    }
    t2s[n * 2 + 0] = di * o0;
    t2s[n * 2 + 1] = di * o1;
}

// ---------------- edge pass 2 + pool: bucketed, per-block partials ---------
// acc2[dloc] = sum t2s[src] (split0 seeds self-loop t2s[d]); then
// pg[batch[d]] += dinv[d]*acc2[d]; counts in split0; row -> partials
__global__ __launch_bounds__(256) void k_e2pool(const unsigned int* __restrict__ bpk, const int* __restrict__ gcnt,
                                                const float* __restrict__ dinv, const float* __restrict__ t2s,
                                                const int* __restrict__ batch,
                                                float* __restrict__ partials, int E, int N) {
    __shared__ float acc2[1024 * NOUT];     // 8 KB
    __shared__ float pg[PSTRIDE];
    int t = threadIdx.x;
    int k = blockIdx.x >> 3, sp = blockIdx.x & (SPLITS_E - 1);
    int nbase = k << 10;
    for (int i = t; i < 1024 * NOUT; i += 256) {
        float v = 0.0f;
        if (sp == 0) {
            int node = nbase + (i >> 1);
            if (node < N) v = t2s[(size_t)node * 2 + (i & 1)];
        }
        acc2[i] = v;
    }
    if (t < PSTRIDE) pg[t] = 0.0f;
    __syncthreads();
    int bstart = gcnt[k * NCB];
    int bend = (k < NBUCK - 1) ? gcnt[(k + 1) * NCB] : E;
    int len = bend - bstart;
    int es = bstart + (int)((long long)len * sp / SPLITS_E);
    int ee = bstart + (int)((long long)len * (sp + 1) / SPLITS_E);
    for (int e = es + t; e < ee; e += 256) {
        unsigned v = bpk[e];
        int s = v & 0x1FFFF;
        int dloc = v >> 17;
        float2 w = *(const float2*)(t2s + (size_t)s * 2);
        atomicAdd(&acc2[dloc * 2 + 0], w.x);
        atomicAdd(&acc2[dloc * 2 + 1], w.y);
    }
    __syncthreads();
    for (int i = t; i < 1024; i += 256) {
        int node = nbase + i;
        if (node < N) {
            float dd = dinv[node];
            int g = batch[node];
            atomicAdd(&pg[g * 2 + 0], dd * acc2[i * 2 + 0]);
            atomicAdd(&pg[g * 2 + 1], dd * acc2[i * 2 + 1]);
            if (sp == 0) atomicAdd(&pg[128 + g], 1.0f);
        }
    }
    __syncthreads();
    if (t < PSTRIDE) partials[(size_t)blockIdx.x * PSTRIDE + t] = pg[t];
}

// ---------------- final: reduce partials, add bias, divide -----------------
__global__ __launch_bounds__(256) void k_final(const float* __restrict__ partials,
                                               const float* __restrict__ b2, float* __restrict__ out) {
    __shared__ float fs[PSTRIDE];
    int t = threadIdx.x;
    if (t < PSTRIDE) {
        float s = 0.0f;
        for (int r = 0; r < NPART; r++) s += partials[(size_t)r * PSTRIDE + t];
        fs[t] = s;
    }
    __syncthreads();
    if (t < NGRAPH * NOUT) {
        int g = t >> 1, c = t & 1;
        float cnt = fs[128 + g];
        out[t] = (fs[t] + cnt * b2[c]) / fmaxf(cnt, 1.0f);
    }
}

extern "C" void kernel_launch(void* const* d_in, const int* in_sizes, int n_in,
                              void* d_out, int out_size, void* d_ws, size_t ws_size,
                              hipStream_t stream) {
    const float* x       = (const float*)d_in[0];
    const float* W1      = (const float*)d_in[1];
    const float* b1      = (const float*)d_in[2];
    const float* prelu_a = (const float*)d_in[3];
    const float* W2      = (const float*)d_in[4];
    const float* b2      = (const float*)d_in[5];
    const int*   ei      = (const int*)d_in[6];
    const int*   batch   = (const int*)d_in[7];

    const int N = in_sizes[7];          // 100000
    const int E = in_sizes[6] / 2;      // 6400000
    const int* src = ei;
    const int* dst = ei + E;

    // workspace layout (4-byte units)
    float* ws       = (float*)d_ws;
    float* deg      = ws;                                   // N (becomes dinv)
    float* h1s      = deg + N;                              // 16N
    float* agg1     = h1s + (size_t)N * HID;                // 16N
    float* t2s      = agg1 + (size_t)N * HID;               // 2N
    int*   gcnt     = (int*)(t2s + (size_t)N * NOUT);       // NBUCK*NCB = 32768
    unsigned int* bpk = (unsigned int*)(gcnt + NBUCK * NCB); // E
    float* partials = (float*)(bpk + E);                    // NPART*PSTRIDE

    float* out = (float*)d_out;

    k_init<<<(N * HID + 255) / 256, 256, 0, stream>>>(agg1, deg, N);
    k_count<<<NCB, 256, 0, stream>>>(dst, gcnt, E);
    k_scan<<<1, 1024, 0, stream>>>(gcnt);
    k_scatter<<<NCB, 256, 0, stream>>>(src, dst, gcnt, bpk, E);
    k_bdeg<<<NBUCK * SPLITS_D, 256, 0, stream>>>(bpk, gcnt, deg, E, N);
    k_dinv<<<(N + 255) / 256, 256, 0, stream>>>(deg, N);
    k_xw1<<<(N + 15) / 16, 256, 0, stream>>>(x, W1, deg, h1s, N);
    k_agg<<<NBUCK * SPLITS_A, 256, 0, stream>>>(bpk, gcnt, h1s, agg1, E, N);
    k_mid<<<(N + 255) / 256, 256, 0, stream>>>(agg1, b1, prelu_a, W2, deg, t2s, N);
    k_e2pool<<<NBUCK * SPLITS_E, 256, 0, stream>>>(bpk, gcnt, deg, t2s, batch, partials, E, N);
    k_final<<<1, 256, 0, stream>>>(partials, b2, out);
}